// Round 1
// baseline (462.522 us; speedup 1.0000x reference)
//
#include <hip/hip_runtime.h>
#include <hip/hip_bf16.h>
#include <stdint.h>

#define B_    256
#define T_    32
#define V_    10000
#define E_    512
#define H_    512
#define NSTEP 31
#define M_    7936      // NSTEP*B_
#define NG_   2048      // 4*H_
#define VPAD_ 10240

typedef __attribute__((ext_vector_type(8))) short  short8;
typedef __attribute__((ext_vector_type(4))) float  f32x4;

static __device__ __forceinline__ unsigned short f2bf(float f) {
  __hip_bfloat16 h = __float2bfloat16(f);
  return *reinterpret_cast<unsigned short*>(&h);
}
static __device__ __forceinline__ ushort4 f4_to_bf4(float4 a) {
  ushort4 r; r.x = f2bf(a.x); r.y = f2bf(a.y); r.z = f2bf(a.z); r.w = f2bf(a.w); return r;
}

#define GLOAD_LDS16(gp, lp)                                                                   \
  __builtin_amdgcn_global_load_lds((const __attribute__((address_space(1))) unsigned int*)(gp), \
                                   (__attribute__((address_space(3))) unsigned int*)(lp), 16, 0, 0)

// ---------------------------------------------------------------- zero out[0]
__global__ __launch_bounds__(256) void k_zero(float* __restrict__ p, int n4) {
  float4 z = make_float4(0.f, 0.f, 0.f, 0.f);
  for (int i = blockIdx.x * 256 + threadIdx.x; i < n4; i += gridDim.x * 256)
    ((float4*)p)[i] = z;
}

// -------------------------------------------------- weights fp32 -> bf16, bias
__global__ __launch_bounds__(256) void k_prep(
    const float* __restrict__ Wih, const float* __restrict__ Whh,
    const float* __restrict__ Wlin, const float* __restrict__ bih,
    const float* __restrict__ bhh,
    unsigned short* __restrict__ Wihb, unsigned short* __restrict__ Whhb,
    unsigned short* __restrict__ Wlb, float* __restrict__ bias) {
  const int stride = gridDim.x * 256;
  const int i0 = blockIdx.x * 256 + threadIdx.x;
  for (int q = i0; q < (NG_ * E_) / 4; q += stride) {
    ((ushort4*)Wihb)[q] = f4_to_bf4(((const float4*)Wih)[q]);
    ((ushort4*)Whhb)[q] = f4_to_bf4(((const float4*)Whh)[q]);
  }
  for (int q = i0; q < (VPAD_ * H_) / 4; q += stride) {
    int row = q >> 7;  // 128 quads per 512-elem row
    ushort4 r;
    if (row < V_) r = f4_to_bf4(((const float4*)Wlin)[q]);
    else { r.x = 0; r.y = 0; r.z = 0; r.w = 0; }
    ((ushort4*)Wlb)[q] = r;
  }
  for (int q = i0; q < NG_; q += stride) bias[q] = bih[q] + bhh[q];
}

// -------------------------------- embedding gather -> bf16 X, h0 -> bf16, c=0
__global__ __launch_bounds__(256) void k_gather(
    const int* __restrict__ caps, const float* __restrict__ embed,
    const float* __restrict__ latent,
    unsigned short* __restrict__ Xbf, unsigned short* __restrict__ h0b,
    float* __restrict__ c) {
  const int stride = gridDim.x * 256;
  const int i0 = blockIdx.x * 256 + threadIdx.x;
  for (int q = i0; q < (M_ * E_) / 4; q += stride) {
    int m = q >> 7;          // row (t*256+b)
    int e4 = q & 127;
    int t = m >> 8, b = m & 255;
    int tok = caps[b * T_ + t];
    float4 a = ((const float4*)(embed + (size_t)tok * E_))[e4];
    ((ushort4*)Xbf)[q] = f4_to_bf4(a);
  }
  float4 z = make_float4(0.f, 0.f, 0.f, 0.f);
  for (int q = i0; q < (B_ * H_) / 4; q += stride) {
    ((ushort4*)h0b)[q] = f4_to_bf4(((const float4*)latent)[q]);
    ((float4*)c)[q] = z;
  }
}

// ------------------------------------------------------------ 128x128 bf16 GEMM
// A [M,512] bf16 row-major, Bt [N,512] bf16 row-major (i.e. op(B)=B^T),
// Out fp32 [M, ldo], out = A*Bt^T + bias (cols >= Nvalid discarded).
__global__ __launch_bounds__(256) void gemm128(
    const unsigned short* __restrict__ A, const unsigned short* __restrict__ Bt,
    const float* __restrict__ bias, float* __restrict__ Out, int ldo, int Nvalid) {
  __shared__ unsigned short As[128 * 32];
  __shared__ unsigned short Bs[128 * 32];
  const int tid = threadIdx.x;
  const int w = tid >> 6, l = tid & 63;
  const int wr = w >> 1, wc = w & 1;
  const int bm = blockIdx.y, bn = blockIdx.x;

  const int srow = (w << 4) + (l >> 2);   // staging row 0..63
  const int skof = (l & 3) << 3;          // k offset in elems
  const unsigned short* ag0 = A + (size_t)(bm * 128 + srow) * 512 + skof;
  const unsigned short* ag1 = ag0 + (size_t)64 * 512;
  const unsigned short* bg0 = Bt + (size_t)(bn * 128 + srow) * 512 + skof;
  const unsigned short* bg1 = bg0 + (size_t)64 * 512;
  unsigned short* al0 = As + ((w << 4)) * 32;
  unsigned short* al1 = As + (64 + (w << 4)) * 32;
  unsigned short* bl0 = Bs + ((w << 4)) * 32;
  unsigned short* bl1 = Bs + (64 + (w << 4)) * 32;

  f32x4 acc[4][4] = {};
  const int lr = l & 15;
  const int lk = (l >> 4) << 3;

  for (int kk = 0; kk < 16; ++kk) {
    const int ko = kk << 5;
    GLOAD_LDS16(ag0 + ko, al0);
    GLOAD_LDS16(ag1 + ko, al1);
    GLOAD_LDS16(bg0 + ko, bl0);
    GLOAD_LDS16(bg1 + ko, bl1);
    __syncthreads();
    short8 af[4], bf8[4];
#pragma unroll
    for (int m = 0; m < 4; ++m)
      af[m] = *(const short8*)(As + (wr * 64 + m * 16 + lr) * 32 + lk);
#pragma unroll
    for (int n = 0; n < 4; ++n)
      bf8[n] = *(const short8*)(Bs + (wc * 64 + n * 16 + lr) * 32 + lk);
#pragma unroll
    for (int m = 0; m < 4; ++m)
#pragma unroll
      for (int n = 0; n < 4; ++n)
        acc[m][n] = __builtin_amdgcn_mfma_f32_16x16x32_bf16(af[m], bf8[n], acc[m][n], 0, 0, 0);
    __syncthreads();
  }

  const int orow0 = bm * 128 + wr * 64 + ((l >> 4) << 2);
  const int ocol0 = bn * 128 + wc * 64 + lr;
#pragma unroll
  for (int n = 0; n < 4; ++n) {
    int col = ocol0 + n * 16;
    if (col < Nvalid) {
      float bb = bias[col];
#pragma unroll
      for (int m = 0; m < 4; ++m) {
        int row = orow0 + m * 16;
#pragma unroll
        for (int r = 0; r < 4; ++r)
          Out[(size_t)(row + r) * ldo + col] = acc[m][n][r] + bb;
      }
    }
  }
}

// --------------------------------------------------- one LSTM step (fused)
// grid (16,8): block = 32 batch rows x 32 h-cols. 4 waves = 4 gate groups.
__global__ __launch_bounds__(256) void k_step(
    const float* __restrict__ Xg_t,           // [256][2048] x@Wih^T + bias
    const unsigned short* __restrict__ Whhb,  // [2048][512] bf16
    const unsigned short* __restrict__ h_in,  // [256][512] bf16
    float* __restrict__ c,                    // [256][512] fp32
    unsigned short* __restrict__ h_out) {     // [256][512] bf16
  __shared__ unsigned short hsh[32 * 512];    // 32 KB, XOR-swizzled chunks
  __shared__ float gsh[4][32 * 32];           // 16 KB
  const int tid = threadIdx.x;
  const int w = tid >> 6, l = tid & 63;
  const int b0 = blockIdx.y << 5;
  const int n0 = blockIdx.x << 5;

  // stage h tile: row `row`, 16B chunk c in LDS holds global chunk c ^ (row&7)
#pragma unroll
  for (int j = 0; j < 8; ++j) {
    int row = (j << 2) + w;
    const unsigned short* g = h_in + (size_t)(b0 + row) * 512 + ((l ^ (row & 7)) << 3);
    GLOAD_LDS16(g, hsh + row * 512);
  }
  __syncthreads();

  const int lr = l & 15;
  f32x4 acc[2][2] = {};
  const unsigned short* wb0 = Whhb + (size_t)(w * 512 + n0 + lr) * 512 + ((l >> 4) << 3);
  const unsigned short* wb1 = wb0 + (size_t)16 * 512;
#pragma unroll
  for (int ks = 0; ks < 16; ++ks) {
    int kc = (ks << 2) + (l >> 4);
    short8 a0 = *(const short8*)(hsh + lr * 512 + ((kc ^ (lr & 7)) << 3));
    short8 a1 = *(const short8*)(hsh + (16 + lr) * 512 + ((kc ^ (lr & 7)) << 3));
    short8 b0v = *(const short8*)(wb0 + (ks << 5));
    short8 b1v = *(const short8*)(wb1 + (ks << 5));
    acc[0][0] = __builtin_amdgcn_mfma_f32_16x16x32_bf16(a0, b0v, acc[0][0], 0, 0, 0);
    acc[0][1] = __builtin_amdgcn_mfma_f32_16x16x32_bf16(a0, b1v, acc[0][1], 0, 0, 0);
    acc[1][0] = __builtin_amdgcn_mfma_f32_16x16x32_bf16(a1, b0v, acc[1][0], 0, 0, 0);
    acc[1][1] = __builtin_amdgcn_mfma_f32_16x16x32_bf16(a1, b1v, acc[1][1], 0, 0, 0);
  }

  const int gr0 = (l >> 4) << 2;
#pragma unroll
  for (int m = 0; m < 2; ++m)
#pragma unroll
    for (int n = 0; n < 2; ++n)
#pragma unroll
      for (int r = 0; r < 4; ++r)
        gsh[w][(m * 16 + gr0 + r) * 32 + n * 16 + lr] = acc[m][n][r];
  __syncthreads();

#pragma unroll
  for (int q = 0; q < 4; ++q) {
    int cell = (q << 8) + tid;
    int br = cell >> 5, nc = cell & 31;
    int gi = (b0 + br) * NG_ + n0 + nc;
    float ig = gsh[0][(br << 5) + nc] + Xg_t[gi];
    float fg = gsh[1][(br << 5) + nc] + Xg_t[gi + 512];
    float gg = gsh[2][(br << 5) + nc] + Xg_t[gi + 1024];
    float og = gsh[3][(br << 5) + nc] + Xg_t[gi + 1536];
    float is = 1.f / (1.f + expf(-ig));
    float fs = 1.f / (1.f + expf(-fg));
    float os = 1.f / (1.f + expf(-og));
    float gt = tanhf(gg);
    int ci = (b0 + br) * 512 + n0 + nc;
    float cn = fs * c[ci] + is * gt;
    c[ci] = cn;
    h_out[ci] = f2bf(os * tanhf(cn));
  }
}

extern "C" void kernel_launch(void* const* d_in, const int* in_sizes, int n_in,
                              void* d_out, int out_size, void* d_ws, size_t ws_size,
                              hipStream_t stream) {
  const int*   caps   = (const int*)d_in[0];
  const float* latent = (const float*)d_in[1];
  const float* embed  = (const float*)d_in[2];
  const float* Wih    = (const float*)d_in[3];
  const float* Whh    = (const float*)d_in[4];
  const float* bih    = (const float*)d_in[5];
  const float* bhh    = (const float*)d_in[6];
  const float* Wlin   = (const float*)d_in[7];
  const float* blin   = (const float*)d_in[8];
  float* out = (float*)d_out;

  char* ws = (char*)d_ws;
  size_t off = 0;
  auto alloc = [&](size_t bytes) {
    void* p = ws + off;
    off = (off + bytes + 255) & ~(size_t)255;
    return p;
  };
  unsigned short* Xbf  = (unsigned short*)alloc((size_t)M_ * E_ * 2);
  unsigned short* Wihb = (unsigned short*)alloc((size_t)NG_ * E_ * 2);
  unsigned short* Whhb = (unsigned short*)alloc((size_t)NG_ * H_ * 2);
  unsigned short* Wlb  = (unsigned short*)alloc((size_t)VPAD_ * H_ * 2);
  float*          bias = (float*)alloc((size_t)NG_ * 4);
  float*          Xg   = (float*)alloc((size_t)M_ * NG_ * 4);
  unsigned short* Hs   = (unsigned short*)alloc((size_t)M_ * H_ * 2);
  unsigned short* h0b  = (unsigned short*)alloc((size_t)B_ * H_ * 2);
  float*          c    = (float*)alloc((size_t)B_ * H_ * 4);
  (void)ws_size; (void)in_sizes; (void)n_in; (void)out_size;

  hipLaunchKernelGGL(k_zero, dim3(1024), dim3(256), 0, stream, out, (B_ * V_) / 4);
  hipLaunchKernelGGL(k_prep, dim3(2048), dim3(256), 0, stream,
                     Wih, Whh, Wlin, bih, bhh, Wihb, Whhb, Wlb, bias);
  hipLaunchKernelGGL(k_gather, dim3(2048), dim3(256), 0, stream,
                     caps, embed, latent, Xbf, h0b, c);
  // Xg = X @ Wih^T + bias   [7936 x 2048]
  hipLaunchKernelGGL(gemm128, dim3(NG_ / 128, M_ / 128), dim3(256), 0, stream,
                     Xbf, Wihb, bias, Xg, NG_, NG_);
  // sequential LSTM steps
  for (int t = 0; t < NSTEP; ++t) {
    const unsigned short* hin = (t == 0) ? h0b : (Hs + (size_t)(t - 1) * B_ * H_);
    hipLaunchKernelGGL(k_step, dim3(16, 8), dim3(256), 0, stream,
                       Xg + (size_t)t * B_ * NG_, Whhb, hin, c,
                       Hs + (size_t)t * B_ * H_);
  }
  // logits = Hs @ Wlin^T + b_lin  -> out rows starting at B_*V_
  hipLaunchKernelGGL(gemm128, dim3(VPAD_ / 128, M_ / 128), dim3(256), 0, stream,
                     Hs, Wlb, blin, out + (size_t)B_ * V_, V_, V_);
}